// Round 6
// baseline (93.273 us; speedup 1.0000x reference)
//
#include <hip/hip_runtime.h>

#ifndef __has_builtin
#define __has_builtin(x) 0
#endif

#if __has_builtin(__builtin_amdgcn_exp2f)
#define EXP2F(x) __builtin_amdgcn_exp2f(x)
#else
#define EXP2F(x) exp2f(x)
#endif

#if __has_builtin(__builtin_amdgcn_rcpf)
#define RCPF(x) __builtin_amdgcn_rcpf(x)
#else
#define RCPF(x) (1.0f / (x))
#endif

namespace {

constexpr int kB = 65536;
constexpr int kT = 50;
constexpr int kI = 2;
constexpr int kH = 20;
constexpr int kO = 2;
constexpr int kGB = 64;    // batch elements per block

__device__ __forceinline__ float fast_tanh(float v) {
    // tanh(v) = 1 - 2/(exp(2v)+1); v_exp_f32 saturates so no clamp needed
    const float p = EXP2F(v * 2.8853900817779268f);
    return fmaf(-2.0f, RCPF(p + 1.0f), 1.0f);
}

// Intra-quad lane exchange via DPP quad_perm (pure VALU, no DS latency).
// xor1: [1,0,3,2]=0xB1  xor2: [2,3,0,1]=0x4E  xor3: [3,2,1,0]=0x1B
#if __has_builtin(__builtin_amdgcn_mov_dpp)
template <int CTRL>
__device__ __forceinline__ float fqp(float v) {
    return __int_as_float(
        __builtin_amdgcn_mov_dpp(__float_as_int(v), CTRL, 0xF, 0xF, true));
}
#else
template <int CTRL>
__device__ __forceinline__ float fqp(float v) {
    constexpr int d = (CTRL == 0xB1) ? 1 : (CTRL == 0x4E) ? 2 : 3;
    return __shfl_xor(v, d);
}
#endif

// 4 threads (one quad) per batch element; thread sub owns hidden rows
// 4*i+sub. W_hh in registers, columns permuted for DPP gather:
//   w[i][r][d] = W_hh[(4i+sub)*20 + (4r + (sub^d))]
// Mask/x prefetch: P/Q ping-pong pair buffers -> loads issued 2 pairs
// (4 steps) before first use, NO register copies (so no early vmcnt drain;
// compiler emits counted waits and the other buffer's loads stay in flight).
__global__ __launch_bounds__(256)
__attribute__((amdgpu_waves_per_eu(2, 4)))
void dprnn_kernel(
    const float* __restrict__ x, const float* __restrict__ W_ih,
    const float* __restrict__ W_hh, const float* __restrict__ b_ih,
    const float* __restrict__ b_hh, const float* __restrict__ W_out,
    const float* __restrict__ b_out, const float* __restrict__ mask,
    float* __restrict__ out)
{
    __shared__ __align__(16) float lds_o[kGB * kT * kO];  // 25600 B

    const int tidx = threadIdx.x;
    const int gl   = tidx >> 2;          // quad index 0..63
    const int sub  = tidx & 3;           // quarter of H owned
    const size_t g = (size_t)blockIdx.x * kGB + gl;

    // ---- weights into registers (column-permuted for DPP gather) ----
    float w[5][5][4];
    float wi0[5], wi1[5], bia[5], wo0[5], wo1[5];
#pragma unroll
    for (int i = 0; i < 5; ++i) {
        const int row = 4 * i + sub;
#pragma unroll
        for (int r = 0; r < 5; ++r)
#pragma unroll
            for (int d = 0; d < 4; ++d)
                w[i][r][d] = W_hh[row * kH + 4 * r + (sub ^ d)];
        wi0[i] = W_ih[row * kI + 0];
        wi1[i] = W_ih[row * kI + 1];
        bia[i] = b_ih[row] + b_hh[row];
        wo0[i] = W_out[row];
        wo1[i] = W_out[kH + row];
    }
    const float bo0 = b_out[0];
    const float bo1 = b_out[1];

    float h[5] = {0.f, 0.f, 0.f, 0.f, 0.f};

    const float* mp = mask + g * (kT * kH) + sub;  // scatter base (stride 4)
    const float* xp = x + g * (kT * kI);

    // one RNN step: masks m[0..4], inputs x0,x1, write slot t
    auto step = [&](const float* m, float x0, float x1, int t) {
        float acc[5];
#pragma unroll
        for (int i = 0; i < 5; ++i)
            acc[i] = fmaf(wi0[i], x0, fmaf(wi1[i], x1, bia[i]));
#pragma unroll
        for (int r = 0; r < 5; ++r) {
            const float v0 = h[r];
            const float v1 = fqp<0xB1>(h[r]);
            const float v2 = fqp<0x4E>(h[r]);
            const float v3 = fqp<0x1B>(h[r]);
#pragma unroll
            for (int i = 0; i < 5; ++i) {
                acc[i] = fmaf(w[i][r][0], v0, acc[i]);
                acc[i] = fmaf(w[i][r][1], v1, acc[i]);
                acc[i] = fmaf(w[i][r][2], v2, acc[i]);
                acc[i] = fmaf(w[i][r][3], v3, acc[i]);
            }
        }
        float p0 = 0.f, p1 = 0.f;
#pragma unroll
        for (int i = 0; i < 5; ++i) {
            const float hn = fast_tanh(acc[i]);
            h[i] = hn;
            const float dm = hn * m[i];
            p0 = fmaf(dm, wo0[i], p0);
            p1 = fmaf(dm, wo1[i], p1);
        }
        p0 += fqp<0xB1>(p0);
        p0 += fqp<0x4E>(p0);
        p1 += fqp<0xB1>(p1);
        p1 += fqp<0x4E>(p1);
        if (sub == 0)
            *(float2*)&lds_o[gl * (kT * kO) + t * kO] =
                make_float2(p0 + bo0, p1 + bo1);
    };

    // P/Q pair buffers: m*[0..4] = first step of pair, m*[5..9] = second
    float mP[10], mQ[10];
    float4 xP, xQ;

    auto load_pair_P = [&](int p) {
        const float* q = mp + p * (2 * kH);
#pragma unroll
        for (int r = 0; r < 5; ++r) {
            mP[r]     = q[4 * r];
            mP[5 + r] = q[kH + 4 * r];
        }
        xP = *(const float4*)(xp + p * 4);
    };
    auto load_pair_Q = [&](int p) {
        const float* q = mp + p * (2 * kH);
#pragma unroll
        for (int r = 0; r < 5; ++r) {
            mQ[r]     = q[4 * r];
            mQ[5 + r] = q[kH + 4 * r];
        }
        xQ = *(const float4*)(xp + p * 4);
    };

    // prologue: pairs 0 (P) and 1 (Q) in flight
    load_pair_P(0);
    load_pair_Q(1);

    // 12 iterations x 2 pairs = pairs 0..23; P reloads 2,4,..,24; Q 3,..,23
#pragma unroll 1
    for (int it = 0; it < 12; ++it) {
        const int e = 2 * it;            // even pair (uses P)
        step(&mP[0], xP.x, xP.y, e * 2);
        step(&mP[5], xP.z, xP.w, e * 2 + 1);
        load_pair_P(e + 2);              // e+2 <= 24 always (it<=11)

        const int o = e + 1;             // odd pair (uses Q)
        step(&mQ[0], xQ.x, xQ.y, o * 2);
        step(&mQ[5], xQ.z, xQ.w, o * 2 + 1);
        if (it < 11) load_pair_Q(o + 2);
    }
    // tail: pair 24 (t = 48, 49), loaded into P at it=11
    step(&mP[0], xP.x, xP.y, 48);
    step(&mP[5], xP.z, xP.w, 49);

    // ---- coalesced writeback of this block's 64*100 floats ----
    __syncthreads();
    float* ob = out + (size_t)blockIdx.x * (kGB * kT * kO);
#pragma unroll
    for (int it = 0; it < 6; ++it) {
        const int idx = it * 1024 + tidx * 4;
        const float4 v = *(const float4*)&lds_o[idx];
        *(float4*)(ob + idx) = v;
    }
    {
        const int idx = 6144 + tidx;
        ob[idx] = lds_o[idx];
    }
}

}  // namespace

extern "C" void kernel_launch(void* const* d_in, const int* in_sizes, int n_in,
                              void* d_out, int out_size, void* d_ws, size_t ws_size,
                              hipStream_t stream) {
    const float* x     = (const float*)d_in[0];
    const float* W_ih  = (const float*)d_in[1];
    const float* W_hh  = (const float*)d_in[2];
    const float* b_ih  = (const float*)d_in[3];
    const float* b_hh  = (const float*)d_in[4];
    const float* W_out = (const float*)d_in[5];
    const float* b_out = (const float*)d_in[6];
    const float* mask  = (const float*)d_in[7];
    float* out = (float*)d_out;

    dim3 block(256);
    dim3 grid(kB / kGB);                 // 1024 blocks
    dprnn_kernel<<<grid, block, 0, stream>>>(x, W_ih, W_hh, b_ih, b_hh,
                                             W_out, b_out, mask, out);
}